// Round 11
// baseline (41.126 us; speedup 1.0000x reference)
//
#include <hip/hip_runtime.h>
#include <hip/hip_bf16.h>

// AFMAttentionLayer: s[b,i,j] = sum_d x[b,i,d]*x[b,j,d]*wsum[d] + bsum
// out = s / denom[b];  denom[b] = sum_d S_d^2*wsum[d] + F*F*bsum (exact fp32 —
// bf16-derived denominators fail: round-5, absmax 82).
//
// Round-11: TRUE async double-buffer. global_load_lds DMA (zero VGPR in-flight
// cost) + raw s_barrier with MINIMAL waitcnt:
//   - mid-iteration barrier: lgkmcnt(0) only (sSp visibility) -> does NOT drain
//     the next tile's DMA (the __syncthreads vmcnt(0)-drain was R10's killer).
//   - end barrier: vmcnt(0), issued after ~2000cy of compute -> free.
// Grid 512, 8 batches/block, 2 blocks/CU. Staging/swizzle/denom/MFMA/store
// logic identical to verified round-9 kernel. B=4096, F=64, D=128, H=4.

constexpr int F = 64;
constexpr int D = 128;

using bf16x8 = __attribute__((ext_vector_type(8))) short;  // 8 bf16 = 4 VGPRs
using f32x4  = __attribute__((ext_vector_type(4))) float;

// pack two f32 -> u32 of 2 bf16 (RNE); compiler emits v_cvt_pk_bf16_f32
__device__ __forceinline__ unsigned pk2(float lo, float hi) {
    float2 f2; f2.x = lo; f2.y = hi;
    __hip_bfloat162 h = __float22bfloat162_rn(f2);
    union { __hip_bfloat162 h2; unsigned u; } cv; cv.h2 = h;
    return cv.u;
}

__global__ __launch_bounds__(256, 2) void afm_kernel(
    const float* __restrict__ x, const float* __restrict__ w,
    const float* __restrict__ bias, float* __restrict__ out)
{
    __shared__ float sX[2][F * D];     // double-buffered fp32 tile (2 x 32 KB)
    __shared__ float sW[D];            // wsum (512 B)
    __shared__ float sSp[8][D];        // per-(rowpar) colsum partials (4 KB)

    const int t      = threadIdx.x;
    const int lane   = t & 63;
    const int wv     = t >> 6;
    const int l31    = lane & 31;
    const int rowpar = t >> 5;         // row & 7 handled by this thread

    if (t < D) sW[t] = w[t] + w[D + t] + w[2 * D + t] + w[3 * D + t];
    const float bsum = bias[0] + bias[1] + bias[2] + bias[3];

    const size_t b0 = (size_t)blockIdx.x * 8;     // 8 batches per block
    const float* xb = x + b0 * (F * D);
    const int cb = l31 ^ rowpar;                  // pre-swizzled source col-block
    const float* srcbase = xb + rowpar * D + cb * 4;

    // DMA one 32KB fp32 tile into sX[buf]; LDS linear, source col pre-swizzled so
    // reads use phys = row*512 + (colByte ^ ((row&7)<<4))   (verified round 9)
    auto STAGE = [&](int buf, int m) {
        const float* sb = srcbase + (size_t)m * (F * D);
        #pragma unroll
        for (int k = 0; k < 8; ++k) {
            __builtin_amdgcn_global_load_lds(
                (const __attribute__((address_space(1))) void*)(sb + k * 8 * D),
                (__attribute__((address_space(3))) void*)(&sX[buf][(k * 4 + wv) * 256]),
                16, 0, 0);
        }
    };

    STAGE(0, 0);
    asm volatile("s_waitcnt vmcnt(0) lgkmcnt(0)\n\ts_barrier" ::: "memory");

    const int fr    = lane & 15;
    const int kgrp  = lane >> 4;
    const int r_a   = wv * 16 + fr;
    const int rowA  = r_a * 512;
    const int swA   = (r_a & 7) << 4;
    const int swB   = (fr & 7) << 4;   // (tj*16+fr)&7 == fr&7
    const int rbase = wv * 16 + 4 * kgrp;

    #pragma unroll 2
    for (int m = 0; m < 8; ++m) {
        const int cur = m & 1;
        if (m < 7) STAGE(cur ^ 1, m + 1);   // in flight across this whole iteration

        const char* sXc = reinterpret_cast<const char*>(&sX[cur][0]);

        // ---- colsum readback (each thread re-reads its own staged slots) ----
        float4 c4 = {0.f, 0.f, 0.f, 0.f};
        #pragma unroll
        for (int k = 0; k < 8; ++k) {
            const float4 v = *reinterpret_cast<const float4*>(&sX[cur][(k * 4 + wv) * 256 + lane * 4]);
            c4.x += v.x; c4.y += v.y; c4.z += v.z; c4.w += v.w;
        }
        *reinterpret_cast<float4*>(&sSp[rowpar][4 * cb]) = c4;
        // sSp visibility only — do NOT drain vmcnt (keeps DMA in flight)
        asm volatile("s_waitcnt lgkmcnt(0)\n\ts_barrier" ::: "memory");

        // ---- exact fp32 denominator (per-wave redundant) ----
        float S0 = 0.f, S1 = 0.f;
        #pragma unroll
        for (int p8 = 0; p8 < 8; ++p8) { S0 += sSp[p8][lane]; S1 += sSp[p8][64 + lane]; }
        float dp = S0 * S0 * sW[lane] + S1 * S1 * sW[64 + lane];
        #pragma unroll
        for (int off = 32; off; off >>= 1) dp += __shfl_xor(dp, off, 64);
        const float rden = 1.0f / (dp + 4096.0f * bsum);

        // ---- MFMA: wave wv computes rows [wv*16, wv*16+16) x all 64 cols ----
        f32x4 acc[4] = {{0,0,0,0},{0,0,0,0},{0,0,0,0},{0,0,0,0}};
        #pragma unroll
        for (int s = 0; s < 4; ++s) {       // K = 32 per step
            const int ch    = 4 * s + kgrp;
            const int cbyte = ch * 32;
            const int aA = rowA + (cbyte ^ swA);
            const float4 a0 = *reinterpret_cast<const float4*>(sXc + aA);
            const float4 a1 = *reinterpret_cast<const float4*>(sXc + (aA ^ 16));
            const float4 wa = *reinterpret_cast<const float4*>(&sW[ch * 8]);
            const float4 wb = *reinterpret_cast<const float4*>(&sW[ch * 8 + 4]);
            union { uint4 u; bf16x8 v; } af;
            af.u.x = pk2(a0.x * wa.x, a0.y * wa.y);
            af.u.y = pk2(a0.z * wa.z, a0.w * wa.w);
            af.u.z = pk2(a1.x * wb.x, a1.y * wb.y);
            af.u.w = pk2(a1.z * wb.z, a1.w * wb.w);
            #pragma unroll
            for (int tj = 0; tj < 4; ++tj) {
                const int aB = (tj * 16 + fr) * 512 + (cbyte ^ swB);
                const float4 bv0 = *reinterpret_cast<const float4*>(sXc + aB);
                const float4 bv1 = *reinterpret_cast<const float4*>(sXc + (aB ^ 16));
                union { uint4 u; bf16x8 v; } bf;
                bf.u.x = pk2(bv0.x, bv0.y); bf.u.y = pk2(bv0.z, bv0.w);
                bf.u.z = pk2(bv1.x, bv1.y); bf.u.w = pk2(bv1.z, bv1.w);
                acc[tj] = __builtin_amdgcn_mfma_f32_16x16x32_bf16(af.v, bf.v, acc[tj], 0, 0, 0);
            }
        }

        // ---- epilogue: C symmetric -> store transpose with float4 stores ----
        float* ob = out + (b0 + m) * (size_t)(F * F);
        #pragma unroll
        for (int tj = 0; tj < 4; ++tj) {
            float4 o;
            o.x = (acc[tj][0] + bsum) * rden;
            o.y = (acc[tj][1] + bsum) * rden;
            o.z = (acc[tj][2] + bsum) * rden;
            o.w = (acc[tj][3] + bsum) * rden;
            *reinterpret_cast<float4*>(ob + (size_t)(tj * 16 + fr) * F + rbase) = o;
        }

        // next tile's DMA done (had the whole compute phase) + all waves done
        // reading buffer cur before its next overwrite
        asm volatile("s_waitcnt vmcnt(0)\n\ts_barrier" ::: "memory");
    }
}

extern "C" void kernel_launch(void* const* d_in, const int* in_sizes, int n_in,
                              void* d_out, int out_size, void* d_ws, size_t ws_size,
                              hipStream_t stream) {
    const float* x  = (const float*)d_in[0];   // [4096, 64, 128]
    const float* w  = (const float*)d_in[1];   // [4, 128]
    const float* b  = (const float*)d_in[2];   // [4]
    float* out      = (float*)d_out;           // [4096, 64, 64]

    afm_kernel<<<512, 256, 0, stream>>>(x, w, b, out);   // 8 batches per block
}

// Round 12
// 36.380 us; speedup vs baseline: 1.1305x; 1.1305x over previous
//
#include <hip/hip_runtime.h>
#include <hip/hip_bf16.h>

// AFMAttentionLayer: s[b,i,j] = sum_d x[b,i,d]*x[b,j,d]*wsum[d] + bsum
// out = s / denom[b];  denom[b] = sum_d S_d^2*wsum[d] + F*F*bsum (exact fp32 —
// bf16-derived denominators fail: round-5 lesson, absmax 82).
// Numerator via bf16 MFMA, single LDS tile; A-fragments derived in-register.
// Round-12 change vs the 36.0us round-4 kernel: epilogue routes C through LDS
// (union with the bf16 tile, XOR-swizzled, conflict-free) so each global store
// instruction writes 1 KB FULLY CONTIGUOUS per wave — testing whether the old
// 16x64B-sector scattered write stream was costing HBM write efficiency.
// B=4096, F=64, D=128, H=4.

constexpr int F = 64;
constexpr int D = 128;

using bf16x8 = __attribute__((ext_vector_type(8))) short;  // 8 bf16 = 4 VGPRs
using f32x4  = __attribute__((ext_vector_type(4))) float;

// Chunked+swizzled LDS tile: chunk = d>>3 (16), row (64), 8 bf16 = 16 B units.
// byte addr = (((chunk<<6)+row)<<4) ^ ((chunk&7)<<4); bank slot16 = (row&7)^(chunk&7).
__device__ __forceinline__ int tile_addr(int chunk, int row) {
    return ((((chunk << 6) + row) << 4) ^ ((chunk & 7) << 4));
}

// pack two f32 -> u32 of 2 bf16 (RNE); compiler emits v_cvt_pk_bf16_f32
__device__ __forceinline__ unsigned pk2(float lo, float hi) {
    float2 f2; f2.x = lo; f2.y = hi;
    __hip_bfloat162 h = __float22bfloat162_rn(f2);
    union { __hip_bfloat162 h2; unsigned u; } cv; cv.h2 = h;
    return cv.u;
}
__device__ __forceinline__ float lo16f(unsigned u) { return __uint_as_float(u << 16); }
__device__ __forceinline__ float hi16f(unsigned u) { return __uint_as_float(u & 0xFFFF0000u); }

__global__ __launch_bounds__(256, 8) void afm_kernel(
    const float* __restrict__ x, const float* __restrict__ w,
    const float* __restrict__ bias, float* __restrict__ out)
{
    // bf16 X tile (16 KB) and fp32 C tile (16 KB) time-share the same LDS
    __shared__ union { short b[F * D]; float c[F * F]; } sT;
    __shared__ float sW[D];            // wsum
    __shared__ float sSp[4][D];        // per-wave column-sum partials (2 KB)

    const int t    = threadIdx.x;
    const int blk  = blockIdx.x;
    const int lane = t & 63;
    const int wv   = t >> 6;

    if (t < D) sW[t] = w[t] + w[D + t] + w[2 * D + t] + w[3 * D + t];
    const float bsum = bias[0] + bias[1] + bias[2] + bias[3];

    // ---- stage bf16(x[blk]) into LDS + per-wave column partial sums ----
    const float* xb = x + (size_t)blk * (F * D);
    const int col   = (4 * t) & 127;        // col quad owned by this thread
    const int chunk = col >> 3;
    const int ebyte = (col & 7) << 1;       // 0 or 8
    float c0 = 0.f, c1 = 0.f, c2 = 0.f, c3 = 0.f;
    char* sBc = reinterpret_cast<char*>(sT.b);

    #pragma unroll
    for (int k = 0; k < 8; ++k) {
        const int f   = k * 1024 + 4 * t;
        const int row = f >> 7;             // = 8k + (t>>5)
        const float4 v = *reinterpret_cast<const float4*>(xb + f);
        c0 += v.x; c1 += v.y; c2 += v.z; c3 += v.w;
        uint2 pb; pb.x = pk2(v.x, v.y); pb.y = pk2(v.z, v.w);
        *reinterpret_cast<uint2*>(sBc + tile_addr(chunk, row) + ebyte) = pb;
    }
    // fold lane^32 (same col quad, other 8 rows of this wave) -> per-wave partials
    c0 += __shfl_xor(c0, 32, 64); c1 += __shfl_xor(c1, 32, 64);
    c2 += __shfl_xor(c2, 32, 64); c3 += __shfl_xor(c3, 32, 64);
    if (lane < 32) {                        // col == 4*lane here
        float4 cs; cs.x = c0; cs.y = c1; cs.z = c2; cs.w = c3;
        *reinterpret_cast<float4*>(&sSp[wv][col]) = cs;
    }
    __syncthreads();   // tile + sW + sSp all visible

    // ---- per-wave denominator (redundant per wave) ----
    const float S0 = sSp[0][lane] + sSp[1][lane] + sSp[2][lane] + sSp[3][lane];
    const float S1 = sSp[0][64 + lane] + sSp[1][64 + lane] + sSp[2][64 + lane] + sSp[3][64 + lane];
    float p = S0 * S0 * sW[lane] + S1 * S1 * sW[64 + lane];
    #pragma unroll
    for (int off = 32; off; off >>= 1) p += __shfl_xor(p, off, 64);
    const float rden = 1.0f / (p + 4096.0f * bsum);

    // ---- MFMA: wave wv computes rows [wv*16, wv*16+16) x all 64 cols ----
    f32x4 acc[4] = {{0,0,0,0},{0,0,0,0},{0,0,0,0},{0,0,0,0}};
    const int fr   = lane & 15;
    const int kgrp = lane >> 4;
    const int r_a  = wv * 16 + fr;

    #pragma unroll
    for (int s = 0; s < 4; ++s) {           // K = 32 per step
        const int ch = 4 * s + kgrp;
        // A fragment: read own bf16 row, unpack -> scale by wsum -> repack
        const uint4  raw = *reinterpret_cast<const uint4*>(sBc + tile_addr(ch, r_a));
        const float4 wa  = *reinterpret_cast<const float4*>(&sW[ch * 8]);
        const float4 wb  = *reinterpret_cast<const float4*>(&sW[ch * 8 + 4]);
        union { uint4 u; bf16x8 v; } af;
        af.u.x = pk2(lo16f(raw.x) * wa.x, hi16f(raw.x) * wa.y);
        af.u.y = pk2(lo16f(raw.y) * wa.z, hi16f(raw.y) * wa.w);
        af.u.z = pk2(lo16f(raw.z) * wb.x, hi16f(raw.z) * wb.y);
        af.u.w = pk2(lo16f(raw.w) * wb.z, hi16f(raw.w) * wb.w);
        #pragma unroll
        for (int tj = 0; tj < 4; ++tj) {
            union { uint4 u; bf16x8 v; } bf;
            bf.u = *reinterpret_cast<const uint4*>(sBc + tile_addr(ch, tj * 16 + fr));
            acc[tj] = __builtin_amdgcn_mfma_f32_16x16x32_bf16(af.v, bf.v, acc[tj], 0, 0, 0);
        }
    }

    // ---- epilogue: C -> LDS (swizzled, conflict-free) -> contiguous stores ----
    __syncthreads();   // all waves done reading the bf16 tile (union reuse)

    char* Cc = reinterpret_cast<char*>(sT.c);
    const int rbase = wv * 16 + 4 * kgrp;
    #pragma unroll
    for (int tj = 0; tj < 4; ++tj) {
        const int row = tj * 16 + fr;       // row&7 == fr&7
        float4 o;
        o.x = (acc[tj][0] + bsum) * rden;
        o.y = (acc[tj][1] + bsum) * rden;
        o.z = (acc[tj][2] + bsum) * rden;
        o.w = (acc[tj][3] + bsum) * rden;
        // Cs[row][rbase..rbase+3], byte XOR-swizzled by ((row&7)<<4)
        *reinterpret_cast<float4*>(Cc + row * 256 + ((rbase * 4) ^ ((row & 7) << 4))) = o;
    }
    __syncthreads();   // C visible

    // each store inst: lane i writes bytes [q*4096 + t*16, +16) -> 1 KB/wave contiguous
    float* ob = out + (size_t)blk * (F * F);
    const int rsw = ((t >> 4) & 7) << 4;    // read-back XOR constant
    #pragma unroll
    for (int q = 0; q < 4; ++q) {
        const float4 v = *reinterpret_cast<const float4*>(Cc + ((q * 4096 + t * 16) ^ rsw));
        *reinterpret_cast<float4*>(reinterpret_cast<char*>(ob) + q * 4096 + t * 16) = v;
    }
}

extern "C" void kernel_launch(void* const* d_in, const int* in_sizes, int n_in,
                              void* d_out, int out_size, void* d_ws, size_t ws_size,
                              hipStream_t stream) {
    const float* x  = (const float*)d_in[0];   // [4096, 64, 128]
    const float* w  = (const float*)d_in[1];   // [4, 128]
    const float* b  = (const float*)d_in[2];   // [4]
    float* out      = (float*)d_out;           // [4096, 64, 64]

    afm_kernel<<<4096, 256, 0, stream>>>(x, w, b, out);
}